// Round 8
// baseline (126.379 us; speedup 1.0000x reference)
//
#include <hip/hip_runtime.h>
#include <hip/hip_fp16.h>

#define POOLED 7
#define PP 49
#define ROI_SCALE 0.25f
#define FH 200
#define FW 304
#define FHW 60800
#define FC 256
#define SR 264            // staging row stride in halves (16B-aligned rows)

// ---------- Pass 1: NCHW fp32 -> NHWC fp16 ----------
__global__ __launch_bounds__(256) void transpose_f16(
    const float* __restrict__ in, __half* __restrict__ out)
{
    __shared__ float tile[64][33];
    const int b   = blockIdx.z;
    const int hw0 = blockIdx.x * 32;
    const int c0  = blockIdx.y * 64;
    const int tx  = threadIdx.x;   // 0..31
    const int ty  = threadIdx.y;   // 0..7

    #pragma unroll
    for (int i = 0; i < 8; i++) {
        int c = c0 + ty + i * 8;
        tile[ty + i * 8][tx] = in[((size_t)b * FC + c) * FHW + hw0 + tx];
    }
    __syncthreads();
    #pragma unroll
    for (int i = 0; i < 4; i++) {
        int hwl = ty + i * 8;
        __half2 h = __floats2half2_rn(tile[2 * tx][hwl], tile[2 * tx + 1][hwl]);
        *reinterpret_cast<__half2*>(
            out + ((size_t)b * FHW + hwl + hw0) * FC + c0 + 2 * tx) = h;
    }
}

// Per-bin interpolation parameters (half-wave x-split baked in).
struct Bin {
    int   row[2][2];   // [iy][lo/hi] = y*FW
    int   xo[2];       // [ix] pixel column for this half-wave
    float wy[2][2];    // [iy][lo/hi] y-weight (valid-masked)
    float wx[2];       // [ix] x-weight for this half-wave (valid-masked)
};

__device__ __forceinline__ void mkbin(int bin, float x1, float y1,
                                      float bin_w, float bin_h, bool hiHalf, Bin& p)
{
    const int ph = bin / 7;
    const int pw = bin - ph * 7;
    #pragma unroll
    for (int iy = 0; iy < 2; iy++) {
        float c = y1 + ((float)(2 * ph + iy) + 0.5f) * 0.5f * bin_h;
        float v = ((c >= -1.0f) && (c <= (float)FH)) ? 1.0f : 0.0f;
        c = fmaxf(c, 0.0f);
        int lo = (int)floorf(c);
        bool edge = (lo >= FH - 1);
        lo = min(lo, FH - 1);
        p.row[iy][0] = lo * FW;
        p.row[iy][1] = min(lo + 1, FH - 1) * FW;
        float ly = edge ? 0.0f : (c - (float)lo);
        p.wy[iy][0] = v * (1.0f - ly);
        p.wy[iy][1] = v * ly;
    }
    #pragma unroll
    for (int ix = 0; ix < 2; ix++) {
        float c = x1 + ((float)(2 * pw + ix) + 0.5f) * 0.5f * bin_w;
        float v = ((c >= -1.0f) && (c <= (float)FW)) ? 1.0f : 0.0f;
        c = fmaxf(c, 0.0f);
        int lo = (int)floorf(c);
        bool edge = (lo >= FW - 1);
        lo = min(lo, FW - 1);
        int hi = min(lo + 1, FW - 1);
        float lx = edge ? 0.0f : (c - (float)lo);
        p.xo[ix] = hiHalf ? hi : lo;
        p.wx[ix] = v * (hiHalf ? lx : (1.0f - lx));
    }
}

__device__ __forceinline__ void ldbin(const __half* base, const Bin& p, uint4* u)
{
    #pragma unroll
    for (int s = 0; s < 4; s++) {
        int iy = s >> 1, ix = s & 1;
        u[2 * s]     = *reinterpret_cast<const uint4*>(base + ((p.row[iy][0] + p.xo[ix]) << 8));
        u[2 * s + 1] = *reinterpret_cast<const uint4*>(base + ((p.row[iy][1] + p.xo[ix]) << 8));
    }
}

__device__ __forceinline__ void fmabin(const Bin& p, const uint4* u, float* acc)
{
    #pragma unroll
    for (int s = 0; s < 4; s++) {
        int iy = s >> 1, ix = s & 1;
        float wlo = p.wy[iy][0] * p.wx[ix];
        float whi = p.wy[iy][1] * p.wx[ix];
        const __half2* hlo = reinterpret_cast<const __half2*>(&u[2 * s]);
        const __half2* hhi = reinterpret_cast<const __half2*>(&u[2 * s + 1]);
        #pragma unroll
        for (int j = 0; j < 4; j++) {
            float2 flo = __half22float2(hlo[j]);
            float2 fhi = __half22float2(hhi[j]);
            acc[2 * j]     += wlo * flo.x + whi * fhi.x;
            acc[2 * j + 1] += wlo * flo.y + whi * fhi.y;
        }
    }
}

__device__ __forceinline__ void finbin(int bin, int c0, bool hiHalf,
                                       float* acc, __half* s_h)
{
    #pragma unroll
    for (int k = 0; k < 8; k++)
        acc[k] += __shfl_xor(acc[k], 32, 64);
    if (!hiHalf) {
        union { __half2 h2[4]; uint4 u; } cv;
        #pragma unroll
        for (int j = 0; j < 4; j++)
            cv.h2[j] = __floats2half2_rn(acc[2 * j] * 0.25f, acc[2 * j + 1] * 0.25f);
        *reinterpret_cast<uint4*>(s_h + bin * SR + c0) = cv.u;
    }
}

// ---------- Pass 2: one block (512 thr, 8 waves) per ROI. ----------
// Wave w owns bins w, w+8, ..., processed TWO at a time (16 loads in flight).
// Lane owns 8 channels (16B). Half-wave split: lanes<32 load the xlo pixel,
// lanes>=32 the xhi pixel. Output staged in fp16 LDS (25.9KB -> 4 blocks/CU,
// 32 waves/CU = full occupancy), then written fully coalesced as fp32.
__global__ __launch_bounds__(512, 8) void roi_gather_f16(
    const __half* __restrict__ f,
    const float* __restrict__ rois,
    float* __restrict__ out)
{
    __shared__ __half s_h[PP * SR];   // 49*264*2 = 25,872 B

    const int n    = blockIdx.x;
    const int tid  = threadIdx.x;
    const int wave = tid >> 6;
    const int lane = tid & 63;
    const int hl   = lane & 31;
    const bool hiHalf = lane >= 32;

    const float* r = rois + (size_t)n * 5;
    const int   bi = (int)r[0];
    const float x1 = r[1] * ROI_SCALE;
    const float y1 = r[2] * ROI_SCALE;
    const float bin_w = fmaxf(r[3] * ROI_SCALE - x1, 1.0f) / (float)POOLED;
    const float bin_h = fmaxf(r[4] * ROI_SCALE - y1, 1.0f) / (float)POOLED;

    const __half* base = f + (size_t)bi * (FHW * FC) + 8 * hl;
    const int c0 = 8 * hl;

    // 3 pairs: (w, w+8), (w+16, w+24), (w+32, w+40); wave 0 also does bin 48.
    #pragma unroll
    for (int pr = 0; pr < 3; pr++) {
        const int binA = wave + 16 * pr;
        const int binB = binA + 8;

        Bin pA, pB;
        mkbin(binA, x1, y1, bin_w, bin_h, hiHalf, pA);
        mkbin(binB, x1, y1, bin_w, bin_h, hiHalf, pB);

        uint4 u[16];
        ldbin(base, pA, u);
        ldbin(base, pB, u + 8);

        float accA[8] = {0.f, 0.f, 0.f, 0.f, 0.f, 0.f, 0.f, 0.f};
        float accB[8] = {0.f, 0.f, 0.f, 0.f, 0.f, 0.f, 0.f, 0.f};
        fmabin(pA, u, accA);
        fmabin(pB, u + 8, accB);

        finbin(binA, c0, hiHalf, accA, s_h);
        finbin(binB, c0, hiHalf, accB, s_h);
    }
    if (wave == 0) {
        Bin p;
        mkbin(48, x1, y1, bin_w, bin_h, hiHalf, p);
        uint4 u[8];
        ldbin(base, p, u);
        float acc[8] = {0.f, 0.f, 0.f, 0.f, 0.f, 0.f, 0.f, 0.f};
        fmabin(p, u, acc);
        finbin(48, c0, hiHalf, acc, s_h);
    }
    __syncthreads();

    // fully coalesced write: out[n][c][bin], consecutive tid -> consecutive addr
    float* ob = out + (size_t)n * (FC * PP);
    for (int i = tid; i < FC * PP; i += 512) {
        int c = i / PP;
        int b = i - c * PP;
        ob[i] = __half2float(s_h[b * SR + c]);
    }
}

// ---------- Fallback (round-1 kernel) if workspace too small ----------
__global__ __launch_bounds__(256) void roi_align_fallback(
    const float* __restrict__ feat,
    const float* __restrict__ rois,
    float* __restrict__ out,
    int C, int H, int W, int N)
{
    int idx = blockIdx.x * blockDim.x + threadIdx.x;
    int total = N * C * PP;
    if (idx >= total) return;

    int pw = idx % POOLED;
    int ph = (idx / POOLED) % POOLED;
    int c  = (idx / PP) % C;
    int n  = idx / (PP * C);

    const float* r = rois + (size_t)n * 5;
    int   b  = (int)r[0];
    float x1 = r[1] * ROI_SCALE;
    float y1 = r[2] * ROI_SCALE;
    float bin_w = fmaxf(r[3] * ROI_SCALE - x1, 1.0f) / (float)POOLED;
    float bin_h = fmaxf(r[4] * ROI_SCALE - y1, 1.0f) / (float)POOLED;

    const float* fc = feat + ((size_t)b * C + c) * (size_t)(H * W);

    float acc = 0.0f;
    #pragma unroll
    for (int iy = 0; iy < 2; iy++) {
        float yy = y1 + ((float)(ph * 2 + iy) + 0.5f) * bin_h * 0.5f;
        bool  vy = (yy >= -1.0f) && (yy <= (float)H);
        float cy = fmaxf(yy, 0.0f);
        int   ylo = (int)floorf(cy);
        bool  ey = (ylo >= H - 1);
        ylo = min(ylo, H - 1);
        int   yhi = min(ylo + 1, H - 1);
        if (ey) cy = (float)ylo;
        float ly = cy - (float)ylo, hy = 1.0f - ly;

        #pragma unroll
        for (int ix = 0; ix < 2; ix++) {
            float xx = x1 + ((float)(pw * 2 + ix) + 0.5f) * bin_w * 0.5f;
            bool  vx = (xx >= -1.0f) && (xx <= (float)W);
            float cx = fmaxf(xx, 0.0f);
            int   xlo = (int)floorf(cx);
            bool  ex = (xlo >= W - 1);
            xlo = min(xlo, W - 1);
            int   xhi = min(xlo + 1, W - 1);
            if (ex) cx = (float)xlo;
            float lx = cx - (float)xlo, hx = 1.0f - lx;

            if (vy && vx) {
                float v11 = fc[(size_t)ylo * W + xlo];
                float v12 = fc[(size_t)ylo * W + xhi];
                float v21 = fc[(size_t)yhi * W + xlo];
                float v22 = fc[(size_t)yhi * W + xhi];
                acc += hy * (hx * v11 + lx * v12) + ly * (hx * v21 + lx * v22);
            }
        }
    }
    out[idx] = acc * 0.25f;
}

extern "C" void kernel_launch(void* const* d_in, const int* in_sizes, int n_in,
                              void* d_out, int out_size, void* d_ws, size_t ws_size,
                              hipStream_t stream) {
    const float* feat = (const float*)d_in[0];
    const float* rois = (const float*)d_in[1];
    float* out = (float*)d_out;

    const int N = in_sizes[1] / 5;
    const int B = in_sizes[0] / (FC * FHW);

    const size_t need = (size_t)B * FHW * FC * sizeof(__half);
    if (ws_size >= need) {
        __half* f16 = (__half*)d_ws;
        transpose_f16<<<dim3(FHW / 32, FC / 64, B), dim3(32, 8), 0, stream>>>(feat, f16);
        roi_gather_f16<<<N, 512, 0, stream>>>(f16, rois, out);
    } else {
        int total = N * FC * PP;
        roi_align_fallback<<<(total + 255) / 256, 256, 0, stream>>>(feat, rois, out, FC, FH, FW, N);
    }
}

// Round 9
// 79.737 us; speedup vs baseline: 1.5850x; 1.5850x over previous
//
#include <hip/hip_runtime.h>
#include <hip/hip_fp16.h>

#define POOLED 7
#define PP 49
#define ROI_SCALE 0.25f
#define FH 200
#define FW 304
#define FHW 60800
#define FC 256
#define RS 271           // s_out row stride (odd => conflict-free read-back)

// ---------- Pass 1: NCHW fp32 -> NHWC fp16 ----------
__global__ __launch_bounds__(256) void transpose_f16(
    const float* __restrict__ in, __half* __restrict__ out)
{
    __shared__ float tile[64][33];
    const int b   = blockIdx.z;
    const int hw0 = blockIdx.x * 32;
    const int c0  = blockIdx.y * 64;
    const int tx  = threadIdx.x;   // 0..31
    const int ty  = threadIdx.y;   // 0..7

    #pragma unroll
    for (int i = 0; i < 8; i++) {
        int c = c0 + ty + i * 8;
        tile[ty + i * 8][tx] = in[((size_t)b * FC + c) * FHW + hw0 + tx];
    }
    __syncthreads();
    #pragma unroll
    for (int i = 0; i < 4; i++) {
        int hwl = ty + i * 8;
        __half2 h = __floats2half2_rn(tile[2 * tx][hwl], tile[2 * tx + 1][hwl]);
        *reinterpret_cast<__half2*>(
            out + ((size_t)b * FHW + hwl + hw0) * FC + c0 + 2 * tx) = h;
    }
}

// Per-bin parameters: 4 pixel offsets (in halves, this half-wave's x) + 8 weights.
struct Bin {
    int   off[4];      // [iy*2+lohi] = (row + x) << 8   (element offset)
    float w[4];        // weight for off[s]: wy[iy][lohi] * wx-combined
    float wx2;         // second x-sample weight ratio handled via two passes
};

// ---------- Pass 2: one block (512 thr, 8 waves) per ROI. ----------
// Wave w owns bins {w,w+8}, {w+16,w+24}, {w+32,w+40} as PAIRS: all 16 pixel
// loads of a pair are issued before any FMA (needs ~120 VGPR -> bounds (512,4)).
// Lane owns 8 channels (16B). Half-wave split: lanes<32 use the xlo pixel,
// lanes>=32 the xhi pixel; one shfl_xor(32) merges. Output staged fp32 in LDS,
// then written fully coalesced.
__global__ __launch_bounds__(512, 4) void roi_gather_f16(
    const __half* __restrict__ f,
    const float* __restrict__ rois,
    float* __restrict__ out)
{
    __shared__ float s_out[PP * RS];   // 53,116 B -> 2 blocks/CU at (512,4)

    const int n    = blockIdx.x;
    const int tid  = threadIdx.x;
    const int wave = tid >> 6;
    const int lane = tid & 63;
    const int hl   = lane & 31;
    const bool hiHalf = lane >= 32;

    const float* r = rois + (size_t)n * 5;
    const int   bi = (int)r[0];
    const float x1 = r[1] * ROI_SCALE;
    const float y1 = r[2] * ROI_SCALE;
    const float bin_w = fmaxf(r[3] * ROI_SCALE - x1, 1.0f) / (float)POOLED;
    const float bin_h = fmaxf(r[4] * ROI_SCALE - y1, 1.0f) / (float)POOLED;

    const __half* base = f + (size_t)bi * (FHW * FC) + 8 * hl;
    const int c0  = 8 * hl;
    const int swz = 2 * (hl >> 2);

    // per-bin param builder (0.25 output scale folded into wx)
    auto mkbin = [&](int bin, int off[8], float w[8]) {
        const int ph = bin / 7;
        const int pw = bin - ph * 7;
        int   row[2][2];
        float wy[2][2];
        #pragma unroll
        for (int iy = 0; iy < 2; iy++) {
            float c = y1 + ((float)(2 * ph + iy) + 0.5f) * 0.5f * bin_h;
            float v = ((c >= -1.0f) && (c <= (float)FH)) ? 1.0f : 0.0f;
            c = fmaxf(c, 0.0f);
            int lo = (int)floorf(c);
            bool edge = (lo >= FH - 1);
            lo = min(lo, FH - 1);
            row[iy][0] = lo * FW;
            row[iy][1] = min(lo + 1, FH - 1) * FW;
            float ly = edge ? 0.0f : (c - (float)lo);
            wy[iy][0] = v * (1.0f - ly);
            wy[iy][1] = v * ly;
        }
        #pragma unroll
        for (int ix = 0; ix < 2; ix++) {
            float c = x1 + ((float)(2 * pw + ix) + 0.5f) * 0.5f * bin_w;
            float v = ((c >= -1.0f) && (c <= (float)FW)) ? 1.0f : 0.0f;
            c = fmaxf(c, 0.0f);
            int lo = (int)floorf(c);
            bool edge = (lo >= FW - 1);
            lo = min(lo, FW - 1);
            int hi = min(lo + 1, FW - 1);
            float lx = edge ? 0.0f : (c - (float)lo);
            int   px = hiHalf ? hi : lo;
            float wx = 0.25f * v * (hiHalf ? lx : (1.0f - lx));
            #pragma unroll
            for (int iy = 0; iy < 2; iy++) {
                off[4 * ix + 2 * iy]     = (row[iy][0] + px) << 8;
                off[4 * ix + 2 * iy + 1] = (row[iy][1] + px) << 8;
                w[4 * ix + 2 * iy]       = wy[iy][0] * wx;
                w[4 * ix + 2 * iy + 1]   = wy[iy][1] * wx;
            }
        }
    };

    auto fma8 = [&](const uint4* u, const float* w, float* acc) {
        #pragma unroll
        for (int s = 0; s < 8; s++) {
            const __half2* h = reinterpret_cast<const __half2*>(&u[s]);
            float ws = w[s];
            #pragma unroll
            for (int j = 0; j < 4; j++) {
                float2 fj = __half22float2(h[j]);
                acc[2 * j]     += ws * fj.x;
                acc[2 * j + 1] += ws * fj.y;
            }
        }
    };

    auto finbin = [&](int bin, float* acc) {
        #pragma unroll
        for (int k = 0; k < 8; k++)
            acc[k] += __shfl_xor(acc[k], 32, 64);
        if (!hiHalf) {
            float* so = s_out + bin * RS + c0 + swz;
            #pragma unroll
            for (int k = 0; k < 8; k++)
                so[k] = acc[k];
        }
    };

    #pragma unroll 1
    for (int pr = 0; pr < 3; pr++) {
        const int binA = wave + 16 * pr;
        const int binB = binA + 8;

        int   offA[8], offB[8];
        float wA[8],  wB[8];
        mkbin(binA, offA, wA);
        mkbin(binB, offB, wB);

        // issue all 16 loads before any use
        uint4 u[16];
        #pragma unroll
        for (int s = 0; s < 8; s++)
            u[s] = *reinterpret_cast<const uint4*>(base + offA[s]);
        #pragma unroll
        for (int s = 0; s < 8; s++)
            u[8 + s] = *reinterpret_cast<const uint4*>(base + offB[s]);

        float accA[8] = {0.f, 0.f, 0.f, 0.f, 0.f, 0.f, 0.f, 0.f};
        float accB[8] = {0.f, 0.f, 0.f, 0.f, 0.f, 0.f, 0.f, 0.f};
        fma8(u, wA, accA);
        fma8(u + 8, wB, accB);

        finbin(binA, accA);
        finbin(binB, accB);
    }
    if (wave == 0) {
        int off[8]; float w[8];
        mkbin(48, off, w);
        uint4 u[8];
        #pragma unroll
        for (int s = 0; s < 8; s++)
            u[s] = *reinterpret_cast<const uint4*>(base + off[s]);
        float acc[8] = {0.f, 0.f, 0.f, 0.f, 0.f, 0.f, 0.f, 0.f};
        fma8(u, w, acc);
        finbin(48, acc);
    }
    __syncthreads();

    // fully coalesced write: out[n][c][bin], consecutive tid -> consecutive addr
    float* ob = out + (size_t)n * (FC * PP);
    for (int i = tid; i < FC * PP; i += 512) {
        int c = i / PP;
        int b = i - c * PP;
        ob[i] = s_out[b * RS + c + 2 * (c >> 5)];
    }
}

// ---------- Fallback (round-1 kernel) if workspace too small ----------
__global__ __launch_bounds__(256) void roi_align_fallback(
    const float* __restrict__ feat,
    const float* __restrict__ rois,
    float* __restrict__ out,
    int C, int H, int W, int N)
{
    int idx = blockIdx.x * blockDim.x + threadIdx.x;
    int total = N * C * PP;
    if (idx >= total) return;

    int pw = idx % POOLED;
    int ph = (idx / POOLED) % POOLED;
    int c  = (idx / PP) % C;
    int n  = idx / (PP * C);

    const float* r = rois + (size_t)n * 5;
    int   b  = (int)r[0];
    float x1 = r[1] * ROI_SCALE;
    float y1 = r[2] * ROI_SCALE;
    float bin_w = fmaxf(r[3] * ROI_SCALE - x1, 1.0f) / (float)POOLED;
    float bin_h = fmaxf(r[4] * ROI_SCALE - y1, 1.0f) / (float)POOLED;

    const float* fc = feat + ((size_t)b * C + c) * (size_t)(H * W);

    float acc = 0.0f;
    #pragma unroll
    for (int iy = 0; iy < 2; iy++) {
        float yy = y1 + ((float)(ph * 2 + iy) + 0.5f) * bin_h * 0.5f;
        bool  vy = (yy >= -1.0f) && (yy <= (float)H);
        float cy = fmaxf(yy, 0.0f);
        int   ylo = (int)floorf(cy);
        bool  ey = (ylo >= H - 1);
        ylo = min(ylo, H - 1);
        int   yhi = min(ylo + 1, H - 1);
        if (ey) cy = (float)ylo;
        float ly = cy - (float)ylo, hy = 1.0f - ly;

        #pragma unroll
        for (int ix = 0; ix < 2; ix++) {
            float xx = x1 + ((float)(pw * 2 + ix) + 0.5f) * bin_w * 0.5f;
            bool  vx = (xx >= -1.0f) && (xx <= (float)W);
            float cx = fmaxf(xx, 0.0f);
            int   xlo = (int)floorf(cx);
            bool  ex = (xlo >= W - 1);
            xlo = min(xlo, W - 1);
            int   xhi = min(xlo + 1, W - 1);
            if (ex) cx = (float)xlo;
            float lx = cx - (float)xlo, hx = 1.0f - lx;

            if (vy && vx) {
                float v11 = fc[(size_t)ylo * W + xlo];
                float v12 = fc[(size_t)ylo * W + xhi];
                float v21 = fc[(size_t)yhi * W + xlo];
                float v22 = fc[(size_t)yhi * W + xhi];
                acc += hy * (hx * v11 + lx * v12) + ly * (hx * v21 + lx * v22);
            }
        }
    }
    out[idx] = acc * 0.25f;
}

extern "C" void kernel_launch(void* const* d_in, const int* in_sizes, int n_in,
                              void* d_out, int out_size, void* d_ws, size_t ws_size,
                              hipStream_t stream) {
    const float* feat = (const float*)d_in[0];
    const float* rois = (const float*)d_in[1];
    float* out = (float*)d_out;

    const int N = in_sizes[1] / 5;
    const int B = in_sizes[0] / (FC * FHW);

    const size_t need = (size_t)B * FHW * FC * sizeof(__half);
    if (ws_size >= need) {
        __half* f16 = (__half*)d_ws;
        transpose_f16<<<dim3(FHW / 32, FC / 64, B), dim3(32, 8), 0, stream>>>(feat, f16);
        roi_gather_f16<<<N, 512, 0, stream>>>(f16, rois, out);
    } else {
        int total = N * FC * PP;
        roi_align_fallback<<<(total + 255) / 256, 256, 0, stream>>>(feat, rois, out, FC, FH, FW, N);
    }
}